// Round 16
// baseline (297.995 us; speedup 1.0000x reference)
//
#include <hip/hip_runtime.h>

#define N_NODES 20000
#define N_EDGES 320000
#define NBINS   (4*N_NODES)
#define SCAN_NBLK 313
#define PRECONV_NBLK 11216
#define HIST_NBLK 1250

typedef unsigned short u16;
typedef __attribute__((ext_vector_type(8))) short bf16x8;
typedef __attribute__((ext_vector_type(4))) float f32x4;
typedef __attribute__((ext_vector_type(4))) unsigned int u32x4;
typedef __attribute__((ext_vector_type(2))) unsigned int u32x2;

__device__ __forceinline__ float b2f(u16 b){
  unsigned u = ((unsigned)b) << 16; float f; __builtin_memcpy(&f, &u, 4); return f;
}
__device__ __forceinline__ u16 f2b(float f){
  unsigned u; __builtin_memcpy(&u, &f, 4); u += 0x7FFF + ((u >> 16) & 1); return (u16)(u >> 16);
}
__device__ __forceinline__ unsigned cvtpk(float a, float b){
  unsigned r;
  asm("v_cvt_pk_bf16_f32 %0, %1, %2" : "=v"(r) : "v"(a), "v"(b));
  return r;
}

// ---------------- fused preconvert + histogram ----------------
#define NX   (N_NODES*128)
#define NW1T (4*288*128)
#define NW2T (4*128*128)
#define NN1  (2*256*128)
#define NN2  (2*128*128)

__global__ void k_prep(const float* __restrict__ x,
                       const float* __restrict__ ew1, const float* __restrict__ ew2,
                       const float* __restrict__ nw1, const float* __restrict__ nw2,
                       u16* __restrict__ x0b,
                       u16* __restrict__ wt1t, u16* __restrict__ wt2t,
                       u16* __restrict__ nw1t, u16* __restrict__ nw2t,
                       const int* __restrict__ ei, const int* __restrict__ ntp,
                       int* __restrict__ hist, int* __restrict__ hist_nt,
                       u16* __restrict__ srank)
{
  int bid = blockIdx.x;
  if (bid >= PRECONV_NBLK) {
    int t = (bid - PRECONV_NBLK) * 256 + threadIdx.x;
    int lane = threadIdx.x & 63;
    if (t < N_EDGES) {
      int r = ei[t], c = ei[N_EDGES + t];
      int tr = ntp[r], tc = ntp[c];
      int key = (tr * 2 + tc) * N_NODES + r;
      int rk = atomicAdd(&hist[key], 1);
      srank[t] = (u16)rk;
    }
    bool valid = t < N_NODES;
    int ty = valid ? ntp[t] : -1;
    unsigned long long m0 = __ballot(ty == 0);
    unsigned long long m1 = __ballot(ty == 1);
    if (lane == 0) {
      int c0 = __popcll(m0), c1 = __popcll(m1);
      if (c0) atomicAdd(&hist_nt[0], c0);
      if (c1) atomicAdd(&hist_nt[1], c1);
    }
    return;
  }
  int t = bid * 256 + threadIdx.x;
  if (t < NX) { x0b[t] = f2b(x[t]); return; }
  t -= NX;
  if (t < NW1T) {
    int p = t / 36864, r = t % 36864; int k = r >> 7, n = r & 127;
    float v = (k < 272) ? ew1[(p * 272 + k) * 128 + n] : 0.f;
    wt1t[(p * 128 + n) * 288 + k] = f2b(v);
    return;
  }
  t -= NW1T;
  if (t < NW2T) {
    int p = t >> 14, r = t & 16383; int k = r >> 7, n = r & 127;
    wt2t[(p * 128 + n) * 128 + k] = f2b(ew2[(p * 128 + k) * 128 + n]);
    return;
  }
  t -= NW2T;
  if (t < NN1) {
    int ty = t >> 15, r = t & 32767; int k = r >> 7, n = r & 127;
    nw1t[(ty * 128 + n) * 256 + k] = f2b(nw1[(ty * 256 + k) * 128 + n]);
    return;
  }
  t -= NN1;
  if (t < NN2) {
    int ty = t >> 14, r = t & 16383; int k = r >> 7, n = r & 127;
    nw2t[(ty * 128 + n) * 128 + k] = f2b(nw2[(ty * 128 + k) * 128 + n]);
  }
}

__global__ void k_scan1(const int* __restrict__ hist, int* __restrict__ parts)
{
  __shared__ int s[256];
  int i = blockIdx.x * 256 + threadIdx.x;
  s[threadIdx.x] = (i < NBINS) ? hist[i] : 0;
  __syncthreads();
  for (int off = 128; off > 0; off >>= 1) {
    if (threadIdx.x < off) s[threadIdx.x] += s[threadIdx.x + off];
    __syncthreads();
  }
  if (threadIdx.x == 0) parts[blockIdx.x] = s[0];
}

__global__ void k_scan2(int* __restrict__ parts)
{
  __shared__ int s[512];
  int t = threadIdx.x;
  int v = (t < SCAN_NBLK) ? parts[t] : 0;
  s[t] = v; __syncthreads();
  for (int off = 1; off < 512; off <<= 1) {
    int xv = (t >= off) ? s[t - off] : 0;
    __syncthreads();
    s[t] += xv;
    __syncthreads();
  }
  if (t < SCAN_NBLK) parts[t] = s[t] - v;
}

__global__ void k_scan3(const int* __restrict__ hist, const int* __restrict__ parts,
                        int* __restrict__ bstart)
{
  __shared__ int s[256];
  int i = blockIdx.x * 256 + threadIdx.x;
  int v = (i < NBINS) ? hist[i] : 0;
  s[threadIdx.x] = v; __syncthreads();
  for (int off = 1; off < 256; off <<= 1) {
    int xv = (threadIdx.x >= off) ? s[threadIdx.x - off] : 0;
    __syncthreads();
    s[threadIdx.x] += xv;
    __syncthreads();
  }
  int excl = s[threadIdx.x] - v + parts[blockIdx.x];
  if (i < NBINS) bstart[i] = excl;
  if (i == 0) bstart[NBINS] = N_EDGES;
}

// ---------------- pass B: placement ----------------
__global__ void k_place(const int* __restrict__ ei, const int* __restrict__ ntp,
                        const u16* __restrict__ srank, const int* __restrict__ bstart,
                        int2* __restrict__ sedge,
                        int* __restrict__ cur_nt, const int* __restrict__ hist_nt,
                        int* __restrict__ nidx)
{
  int t = blockIdx.x * 256 + threadIdx.x;
  int lane = threadIdx.x & 63;
  if (t < N_EDGES) {
    int r = ei[t], c = ei[N_EDGES + t];
    int tr = ntp[r], tc = ntp[c];
    int key = (tr * 2 + tc) * N_NODES + r;
    int pos = bstart[key] + (int)srank[t];
    int2 v; v.x = r | (c << 15); v.y = t;
    sedge[pos] = v;
  }
  bool valid = t < N_NODES;
  int ty = valid ? ntp[t] : -1;
  unsigned long long m0 = __ballot(ty == 0);
  unsigned long long m1 = __ballot(ty == 1);
  int b0 = 0, b1 = 0;
  if (lane == 0) {
    int c0 = __popcll(m0), c1 = __popcll(m1);
    if (c0) b0 = atomicAdd(&cur_nt[0], c0);
    if (c1) b1 = atomicAdd(&cur_nt[1], c1);
  }
  b0 = __shfl(b0, 0); b1 = __shfl(b1, 0);
  if (valid) {
    unsigned long long lt = (1ull << lane) - 1ull;
    int pos = (ty == 0) ? (b0 + __popcll(m0 & lt))
                        : (hist_nt[0] + b1 + __popcll(m1 & lt));
    nidx[pos] = t;
  }
}

// ---------------- edge MLP v14: v13 gather-prefetch + launch_bounds(512,1) (lift 128-VGPR cap) ----------------
// LDS already pins occupancy at 1 block/CU = 2 waves/SIMD, so allowing up to 256 VGPRs is free.
__launch_bounds__(512, 1)
__global__ void k_edge(const u16* __restrict__ x0b, const float* __restrict__ ea,
                       const u16* __restrict__ wt1t, const u16* __restrict__ wt2t,
                       const float* __restrict__ eb1, const float* __restrict__ eb2,
                       const int* __restrict__ bstart, const int2* __restrict__ sedge,
                       u16* __restrict__ h2s)
{
  __shared__ u16 sW1[36 * 1024];      // [chunk][n 128][8]
  __shared__ u16 sW2[16 * 1024];      // [chunk][n 128][8]
  __shared__ u16 slab[8][16 * 128];   // per-wave [chunk 16][llo 16][8]
  __shared__ float sEb1[128];
  __shared__ float sEb2[128];

  const int p    = blockIdx.y;
  const int tid  = threadIdx.x;
  const int lane = tid & 63;
  const int wv   = tid >> 6;
  const int llo  = lane & 15;
  const int lhi  = lane >> 4;

  const int base_p = bstart[p * N_NODES];
  const int end_p  = bstart[(p + 1) * N_NODES];

  // stage weights once per block (chunk-major)
  for (int i = tid; i < 128 * 36; i += 512) {
    int n = i / 36, c = i % 36;
    *(u32x4*)&sW1[(c * 128 + n) * 8] = *(const u32x4*)&wt1t[(p * 128 + n) * 288 + c * 8];
  }
  for (int i = tid; i < 128 * 16; i += 512) {
    int n = i >> 4, c = i & 15;
    *(u32x4*)&sW2[(c * 128 + n) * 8] = *(const u32x4*)&wt2t[(p * 128 + n) * 128 + c * 8];
  }
  if (tid < 128) sEb1[tid] = eb1[p * 128 + tid];
  else if (tid < 256) sEb2[tid - 128] = eb2[p * 128 + tid - 128];
  __syncthreads();   // only block-wide barrier

  u16* myslab = &slab[wv][0];
  const int np = end_p - base_p;
  if (np <= 0) return;
  const int ngrp = (np + 31) >> 5;

  // contiguous span of 32-edge groups for this block (row-sorted -> L2 locality)
  const int g0 = (int)(((long long)blockIdx.x * ngrp) / 64);
  const int g1 = (int)(((long long)(blockIdx.x + 1) * ngrp) / 64);

  int g = g0 + wv;
  if (g >= g1) return;

  // current-tile operands (refilled at the end of each iteration)
  bf16x8 xr[2][4], xc[2][4], eaf[2];
  int sp0, sp1;          // store positions of the CURRENT tile
  int2 mN0, mN1;         // metadata for the NEXT tile

  // prologue: load meta(T0), gather operands(T0), prefetch meta(T1)
  {
    const int es = base_p + g * 32;
    sp0 = es + llo; sp1 = sp0 + 16;
    int q0 = sp0 < end_p ? sp0 : end_p - 1;
    int q1 = sp1 < end_p ? sp1 : end_p - 1;
    int2 m0 = sedge[q0];
    int2 m1 = sedge[q1];
    const int row0 = m0.x & 32767, col0 = m0.x >> 15, eid0 = m0.y;
    const int row1 = m1.x & 32767, col1 = m1.x >> 15, eid1 = m1.y;
    #pragma unroll
    for (int ck = 0; ck < 4; ++ck) {
      xr[0][ck] = *(const bf16x8*)&x0b[row0 * 128 + ck * 32 + lhi * 8];
      xc[0][ck] = *(const bf16x8*)&x0b[col0 * 128 + ck * 32 + lhi * 8];
      xr[1][ck] = *(const bf16x8*)&x0b[row1 * 128 + ck * 32 + lhi * 8];
      xc[1][ck] = *(const bf16x8*)&x0b[col1 * 128 + ck * 32 + lhi * 8];
    }
    u32x4 pk0 = (u32x4){0u,0u,0u,0u}, pk1 = (u32x4){0u,0u,0u,0u};
    if (lhi < 2) {
      f32x4 f0 = *(const f32x4*)&ea[eid0 * 16 + lhi * 8];
      f32x4 f1 = *(const f32x4*)&ea[eid0 * 16 + lhi * 8 + 4];
      pk0[0] = cvtpk(f0[0], f0[1]); pk0[1] = cvtpk(f0[2], f0[3]);
      pk0[2] = cvtpk(f1[0], f1[1]); pk0[3] = cvtpk(f1[2], f1[3]);
      f32x4 h0 = *(const f32x4*)&ea[eid1 * 16 + lhi * 8];
      f32x4 h1 = *(const f32x4*)&ea[eid1 * 16 + lhi * 8 + 4];
      pk1[0] = cvtpk(h0[0], h0[1]); pk1[1] = cvtpk(h0[2], h0[3]);
      pk1[2] = cvtpk(h1[0], h1[1]); pk1[3] = cvtpk(h1[2], h1[3]);
    }
    __builtin_memcpy(&eaf[0], &pk0, 16);
    __builtin_memcpy(&eaf[1], &pk1, 16);

    const int gn = g + 8;
    if (gn < g1) {
      const int esn = base_p + gn * 32;
      int r0 = esn + llo;      r0 = r0 < end_p ? r0 : end_p - 1;
      int r1 = esn + 16 + llo; r1 = r1 < end_p ? r1 : end_p - 1;
      mN0 = sedge[r0];
      mN1 = sedge[r1];
    }
  }

  for (; g < g1; g += 8) {
    const bool hn = (g + 8) < g1;

    // ---- layer 1: K = 256 (row|col) + 32 (ea) — consumes xr/xc/eaf ----
    f32x4 acc[8][2];
    #pragma unroll
    for (int i = 0; i < 8; ++i) {
      acc[i][0] = (f32x4){0.f, 0.f, 0.f, 0.f};
      acc[i][1] = (f32x4){0.f, 0.f, 0.f, 0.f};
    }

    #pragma unroll
    for (int ck = 0; ck < 4; ++ck) {
      #pragma unroll
      for (int i = 0; i < 8; ++i) {
        bf16x8 wa = *(const bf16x8*)&sW1[((ck * 4 + lhi) * 128 + i * 16 + llo) * 8];
        acc[i][0] = __builtin_amdgcn_mfma_f32_16x16x32_bf16(wa, xr[0][ck], acc[i][0], 0, 0, 0);
        acc[i][1] = __builtin_amdgcn_mfma_f32_16x16x32_bf16(wa, xr[1][ck], acc[i][1], 0, 0, 0);
      }
    }
    #pragma unroll
    for (int ck = 0; ck < 4; ++ck) {
      #pragma unroll
      for (int i = 0; i < 8; ++i) {
        bf16x8 wb = *(const bf16x8*)&sW1[((16 + ck * 4 + lhi) * 128 + i * 16 + llo) * 8];
        acc[i][0] = __builtin_amdgcn_mfma_f32_16x16x32_bf16(wb, xc[0][ck], acc[i][0], 0, 0, 0);
        acc[i][1] = __builtin_amdgcn_mfma_f32_16x16x32_bf16(wb, xc[1][ck], acc[i][1], 0, 0, 0);
      }
    }
    #pragma unroll
    for (int i = 0; i < 8; ++i) {
      bf16x8 wce = *(const bf16x8*)&sW1[((32 + lhi) * 128 + i * 16 + llo) * 8];
      acc[i][0] = __builtin_amdgcn_mfma_f32_16x16x32_bf16(wce, eaf[0], acc[i][0], 0, 0, 0);
      acc[i][1] = __builtin_amdgcn_mfma_f32_16x16x32_bf16(wce, eaf[1], acc[i][1], 0, 0, 0);
    }

    // h1 = relu(acc+eb1): transpose via per-wave slab (chunk-major), collect B-frags
    bf16x8 h1f[2][4];
    #pragma unroll
    for (int j = 0; j < 2; ++j) {
      #pragma unroll
      for (int i = 0; i < 8; ++i) {
        const f32x4 bb = *(const f32x4*)&sEb1[i * 16 + lhi * 4];
        float v0 = acc[i][j][0] + bb[0]; v0 = v0 > 0.f ? v0 : 0.f;
        float v1 = acc[i][j][1] + bb[1]; v1 = v1 > 0.f ? v1 : 0.f;
        float v2 = acc[i][j][2] + bb[2]; v2 = v2 > 0.f ? v2 : 0.f;
        float v3 = acc[i][j][3] + bb[3]; v3 = v3 > 0.f ? v3 : 0.f;
        u32x2 pk; pk[0] = cvtpk(v0, v1); pk[1] = cvtpk(v2, v3);
        *(u32x2*)&myslab[((2 * i + (lhi >> 1)) * 16 + llo) * 8 + (lhi & 1) * 4] = pk;
      }
      #pragma unroll
      for (int ck = 0; ck < 4; ++ck)
        h1f[j][ck] = *(const bf16x8*)&myslab[((ck * 4 + lhi) * 16 + llo) * 8];
    }

    // xr/xc/eaf are dead now — refill with NEXT tile's operands (latency drains under layer2)
    int np0 = sp0, np1 = sp1;
    if (hn) {
      const int esn = base_p + (g + 8) * 32;
      np0 = esn + llo; np1 = np0 + 16;
      const int row0 = mN0.x & 32767, col0 = mN0.x >> 15, eid0 = mN0.y;
      const int row1 = mN1.x & 32767, col1 = mN1.x >> 15, eid1 = mN1.y;
      #pragma unroll
      for (int ck = 0; ck < 4; ++ck) {
        xr[0][ck] = *(const bf16x8*)&x0b[row0 * 128 + ck * 32 + lhi * 8];
        xc[0][ck] = *(const bf16x8*)&x0b[col0 * 128 + ck * 32 + lhi * 8];
        xr[1][ck] = *(const bf16x8*)&x0b[row1 * 128 + ck * 32 + lhi * 8];
        xc[1][ck] = *(const bf16x8*)&x0b[col1 * 128 + ck * 32 + lhi * 8];
      }
      u32x4 pk0 = (u32x4){0u,0u,0u,0u}, pk1 = (u32x4){0u,0u,0u,0u};
      if (lhi < 2) {
        f32x4 f0 = *(const f32x4*)&ea[eid0 * 16 + lhi * 8];
        f32x4 f1 = *(const f32x4*)&ea[eid0 * 16 + lhi * 8 + 4];
        pk0[0] = cvtpk(f0[0], f0[1]); pk0[1] = cvtpk(f0[2], f0[3]);
        pk0[2] = cvtpk(f1[0], f1[1]); pk0[3] = cvtpk(f1[2], f1[3]);
        f32x4 h0 = *(const f32x4*)&ea[eid1 * 16 + lhi * 8];
        f32x4 h1 = *(const f32x4*)&ea[eid1 * 16 + lhi * 8 + 4];
        pk1[0] = cvtpk(h0[0], h0[1]); pk1[1] = cvtpk(h0[2], h0[3]);
        pk1[2] = cvtpk(h1[0], h1[1]); pk1[3] = cvtpk(h1[2], h1[3]);
      }
      __builtin_memcpy(&eaf[0], &pk0, 16);
      __builtin_memcpy(&eaf[1], &pk1, 16);

      // prefetch meta for T(k+2)
      const int gnn = g + 16;
      if (gnn < g1) {
        const int esnn = base_p + gnn * 32;
        int r0 = esnn + llo;      r0 = r0 < end_p ? r0 : end_p - 1;
        int r1 = esnn + 16 + llo; r1 = r1 < end_p ? r1 : end_p - 1;
        mN0 = sedge[r0];
        mN1 = sedge[r1];
      }
    }

    // ---- layer 2: K = 128, W2 from LDS (chunk-major) ----
    f32x4 o[8][2];
    #pragma unroll
    for (int i = 0; i < 8; ++i) {
      o[i][0] = (f32x4){0.f, 0.f, 0.f, 0.f};
      o[i][1] = (f32x4){0.f, 0.f, 0.f, 0.f};
    }
    #pragma unroll
    for (int ck = 0; ck < 4; ++ck) {
      #pragma unroll
      for (int i = 0; i < 8; ++i) {
        bf16x8 w2f = *(const bf16x8*)&sW2[((ck * 4 + lhi) * 128 + i * 16 + llo) * 8];
        o[i][0] = __builtin_amdgcn_mfma_f32_16x16x32_bf16(w2f, h1f[0][ck], o[i][0], 0, 0, 0);
        o[i][1] = __builtin_amdgcn_mfma_f32_16x16x32_bf16(w2f, h1f[1][ck], o[i][1], 0, 0, 0);
      }
    }

    // h2 = relu(o + eb2) -> packed 8B stores at CURRENT tile's sorted positions
    #pragma unroll
    for (int i = 0; i < 8; ++i) {
      const f32x4 bb = *(const f32x4*)&sEb2[i * 16 + lhi * 4];
      {
        float v0 = o[i][0][0] + bb[0]; v0 = v0 > 0.f ? v0 : 0.f;
        float v1 = o[i][0][1] + bb[1]; v1 = v1 > 0.f ? v1 : 0.f;
        float v2 = o[i][0][2] + bb[2]; v2 = v2 > 0.f ? v2 : 0.f;
        float v3 = o[i][0][3] + bb[3]; v3 = v3 > 0.f ? v3 : 0.f;
        u32x2 pk; pk[0] = cvtpk(v0, v1); pk[1] = cvtpk(v2, v3);
        if (sp0 < end_p) *(u32x2*)&h2s[sp0 * 128 + i * 16 + lhi * 4] = pk;
      }
      {
        float v0 = o[i][1][0] + bb[0]; v0 = v0 > 0.f ? v0 : 0.f;
        float v1 = o[i][1][1] + bb[1]; v1 = v1 > 0.f ? v1 : 0.f;
        float v2 = o[i][1][2] + bb[2]; v2 = v2 > 0.f ? v2 : 0.f;
        float v3 = o[i][1][3] + bb[3]; v3 = v3 > 0.f ? v3 : 0.f;
        u32x2 pk; pk[0] = cvtpk(v0, v1); pk[1] = cvtpk(v2, v3);
        if (sp1 < end_p) *(u32x2*)&h2s[sp1 * 128 + i * 16 + lhi * 4] = pk;
      }
    }

    sp0 = np0; sp1 = np1;
  }
}

// ---------------- node MLP: persistent blocks, weights staged once ----------------
__launch_bounds__(512, 1)
__global__ void k_node(const u16* __restrict__ x0b, const float* __restrict__ xf,
                       const u16* __restrict__ h2s,
                       const u16* __restrict__ nw1t, const u16* __restrict__ nw2t,
                       const float* __restrict__ nb1, const float* __restrict__ nb2,
                       const int* __restrict__ bstart,
                       const int* __restrict__ nidx, const int* __restrict__ hist_nt,
                       float* __restrict__ out)
{
  const int ty    = blockIdx.y;
  const int cnt0  = hist_nt[0];
  const int cnt_t = ty ? (N_NODES - cnt0) : cnt0;
  const int base_t = ty ? cnt0 : 0;

  __shared__ u16 sNIN[64 * 264];
  __shared__ u16 sNW1[128 * 264];
  __shared__ u16 sNW2[128 * 136];
  __shared__ float sNb1[128];
  __shared__ float sNb2[128];
  __shared__ int sNid[64];

  const int tid  = threadIdx.x;
  const int lane = tid & 63;
  const int wid  = tid >> 6;
  const int llo  = lane & 15;
  const int lhi  = lane >> 4;

  for (int i = tid; i < 128 * 256; i += 512) {
    int n = i >> 8, k = i & 255;
    sNW1[n * 264 + k] = nw1t[(ty * 128 + n) * 256 + k];
  }
  for (int i = tid; i < 128 * 128; i += 512) {
    int n = i >> 7, k = i & 127;
    sNW2[n * 136 + k] = nw2t[(ty * 128 + n) * 128 + k];
  }
  if (tid < 128) { sNb1[tid] = nb1[ty * 128 + tid]; sNb2[tid] = nb2[ty * 128 + tid]; }
  __syncthreads();

  for (int t0 = blockIdx.x * 64; t0 < cnt_t; t0 += gridDim.x * 64) {
    const int cnt = min(64, cnt_t - t0);
    if (tid < 64) {
      int nid = 0;
      if (tid < cnt) nid = nidx[base_t + t0 + tid];
      sNid[tid] = nid;
    }
    __syncthreads();

    {
      const int m = tid >> 3, qq = tid & 7;
      const int nid = sNid[m];
      const u16* xs = &x0b[nid * 128 + qq * 16];
      u16* dst = &sNIN[m * 264 + qq * 16];
      #pragma unroll
      for (int j = 0; j < 2; ++j) *(u32x4*)(dst + j * 8) = *(const u32x4*)(xs + j * 8);

      float a[16];
      #pragma unroll
      for (int j = 0; j < 16; ++j) a[j] = 0.f;
      #pragma unroll
      for (int pr = 0; pr < 2; ++pr) {
        const int key = (ty * 2 + pr) * N_NODES + nid;
        const int s = bstart[key], e = bstart[key + 1];
        for (int pos = s; pos < e; ++pos) {
          const u16* hp = &h2s[pos * 128 + qq * 16];
          #pragma unroll
          for (int j = 0; j < 2; ++j) {
            u32x4 v = *(const u32x4*)(hp + j * 8);
            #pragma unroll
            for (int w = 0; w < 4; ++w) {
              unsigned uu = v[w];
              a[j * 8 + w * 2 + 0] += b2f((u16)(uu & 0xFFFFu));
              a[j * 8 + w * 2 + 1] += b2f((u16)(uu >> 16));
            }
          }
        }
      }
      u16* ad = &sNIN[m * 264 + 128 + qq * 16];
      #pragma unroll
      for (int j = 0; j < 8; ++j) {
        unsigned pk = cvtpk(a[2 * j], a[2 * j + 1]);
        *(unsigned*)(ad + 2 * j) = pk;
      }
    }
    __syncthreads();

    f32x4 acc[4];
    #pragma unroll
    for (int i = 0; i < 4; ++i) acc[i] = (f32x4){0.f, 0.f, 0.f, 0.f};

    #pragma unroll
    for (int ck = 0; ck < 8; ++ck) {
      const int kk = ck * 32 + lhi * 8;
      bf16x8 a[4], b;
      #pragma unroll
      for (int i = 0; i < 4; ++i)
        a[i] = *(const bf16x8*)&sNIN[(i * 16 + llo) * 264 + kk];
      b = *(const bf16x8*)&sNW1[(wid * 16 + llo) * 264 + kk];
      #pragma unroll
      for (int i = 0; i < 4; ++i)
        acc[i] = __builtin_amdgcn_mfma_f32_16x16x32_bf16(a[i], b, acc[i], 0, 0, 0);
    }
    __syncthreads();

    u16* sH1 = sNIN;
    #pragma unroll
    for (int i = 0; i < 4; ++i) {
      const int c = wid * 16 + llo;
      const float bias = sNb1[c];
      #pragma unroll
      for (int r = 0; r < 4; ++r) {
        const int m = i * 16 + lhi * 4 + r;
        float v = acc[i][r] + bias;
        v = v > 0.f ? v : 0.f;
        sH1[m * 136 + c] = f2b(v);
      }
    }
    __syncthreads();

    #pragma unroll
    for (int i = 0; i < 4; ++i) acc[i] = (f32x4){0.f, 0.f, 0.f, 0.f};

    #pragma unroll
    for (int ck = 0; ck < 4; ++ck) {
      const int kk = ck * 32 + lhi * 8;
      bf16x8 a[4], b;
      #pragma unroll
      for (int i = 0; i < 4; ++i)
        a[i] = *(const bf16x8*)&sH1[(i * 16 + llo) * 136 + kk];
      b = *(const bf16x8*)&sNW2[(wid * 16 + llo) * 136 + kk];
      #pragma unroll
      for (int i = 0; i < 4; ++i)
        acc[i] = __builtin_amdgcn_mfma_f32_16x16x32_bf16(a[i], b, acc[i], 0, 0, 0);
    }

    #pragma unroll
    for (int i = 0; i < 4; ++i) {
      const int c = wid * 16 + llo;
      const float bias = sNb2[c];
      #pragma unroll
      for (int r = 0; r < 4; ++r) {
        const int m = i * 16 + lhi * 4 + r;
        if (m < cnt) {
          const int nid = sNid[m];
          out[nid * 128 + c] = acc[i][r] + bias + xf[nid * 128 + c];
        }
      }
    }
    __syncthreads();
  }
}

// ---------------- launch ----------------
extern "C" void kernel_launch(void* const* d_in, const int* in_sizes, int n_in,
                              void* d_out, int out_size, void* d_ws, size_t ws_size,
                              hipStream_t stream)
{
  const float* x   = (const float*)d_in[0];
  const int*   ei  = (const int*)d_in[1];
  const float* ea  = (const float*)d_in[2];
  const int*   ntp = (const int*)d_in[3];
  const float* ew1 = (const float*)d_in[4];
  const float* eb1 = (const float*)d_in[5];
  const float* ew2 = (const float*)d_in[6];
  const float* eb2 = (const float*)d_in[7];
  const float* nw1 = (const float*)d_in[8];
  const float* nb1 = (const float*)d_in[9];
  const float* nw2 = (const float*)d_in[10];
  const float* nb2 = (const float*)d_in[11];

  char* ws = (char*)d_ws;
  int*  hist    = (int*)(ws + 0);          // 320000
  int*  hist_nt = (int*)(ws + 320000);     // 8
  int*  cur_nt  = (int*)(ws + 320008);     // 8
  int*  parts   = (int*)(ws + 320256);     // 1252
  int*  bstart  = (int*)(ws + 321792);     // 320004
  u16*  srank   = (u16*)(ws + 641824);     // 640000
  int2* sedge   = (int2*)(ws + 1281824);   // 2560000
  int*  nidx    = (int*)(ws + 3841824);    // 80000
  u16*  x0b     = (u16*)(ws + 3921824);    // 5120000
  u16*  wt1t    = (u16*)(ws + 9041824);    // 294912
  u16*  wt2t    = (u16*)(ws + 9336736);    // 131072
  u16*  nw1t    = (u16*)(ws + 9467808);    // 131072
  u16*  nw2t    = (u16*)(ws + 9598880);    // 65536
  u16*  h2s     = (u16*)(ws + 9664416);    // 81920000 -> total ~91.6 MB (known-good)

  hipMemsetAsync(ws, 0, 320016, stream);
  k_prep<<<PRECONV_NBLK + HIST_NBLK, 256, 0, stream>>>(
      x, ew1, ew2, nw1, nw2, x0b, wt1t, wt2t, nw1t, nw2t,
      ei, ntp, hist, hist_nt, srank);
  k_scan1<<<SCAN_NBLK, 256, 0, stream>>>(hist, parts);
  k_scan2<<<1, 512, 0, stream>>>(parts);
  k_scan3<<<SCAN_NBLK, 256, 0, stream>>>(hist, parts, bstart);
  k_place<<<1250, 256, 0, stream>>>(ei, ntp, srank, bstart, sedge, cur_nt, hist_nt, nidx);
  k_edge<<<dim3(64, 4), 512, 0, stream>>>(x0b, ea, wt1t, wt2t, eb1, eb2, bstart, sedge, h2s);
  k_node<<<dim3(160, 2), 512, 0, stream>>>(x0b, x, h2s, nw1t, nw2t, nb1, nb2, bstart, nidx, hist_nt, (float*)d_out);
}

// Round 17
// 159.277 us; speedup vs baseline: 1.8709x; 1.8709x over previous
//
#include <hip/hip_runtime.h>

#define N_NODES 20000
#define N_EDGES 320000
#define NBINS   (4*N_NODES)
#define SCAN_NBLK 313
#define PRECONV_NBLK 11216
#define HIST_NBLK 1250

typedef unsigned short u16;
typedef __attribute__((ext_vector_type(8))) short bf16x8;
typedef __attribute__((ext_vector_type(4))) float f32x4;
typedef __attribute__((ext_vector_type(4))) unsigned int u32x4;
typedef __attribute__((ext_vector_type(2))) unsigned int u32x2;

__device__ __forceinline__ float b2f(u16 b){
  unsigned u = ((unsigned)b) << 16; float f; __builtin_memcpy(&f, &u, 4); return f;
}
__device__ __forceinline__ u16 f2b(float f){
  unsigned u; __builtin_memcpy(&u, &f, 4); u += 0x7FFF + ((u >> 16) & 1); return (u16)(u >> 16);
}
__device__ __forceinline__ unsigned cvtpk(float a, float b){
  unsigned r;
  asm("v_cvt_pk_bf16_f32 %0, %1, %2" : "=v"(r) : "v"(a), "v"(b));
  return r;
}

// ---------------- fused preconvert + histogram ----------------
#define NX   (N_NODES*128)
#define NW1T (4*288*128)
#define NW2T (4*128*128)
#define NN1  (2*256*128)
#define NN2  (2*128*128)

__global__ void k_prep(const float* __restrict__ x,
                       const float* __restrict__ ew1, const float* __restrict__ ew2,
                       const float* __restrict__ nw1, const float* __restrict__ nw2,
                       u16* __restrict__ x0b,
                       u16* __restrict__ wt1t, u16* __restrict__ wt2t,
                       u16* __restrict__ nw1t, u16* __restrict__ nw2t,
                       const int* __restrict__ ei, const int* __restrict__ ntp,
                       int* __restrict__ hist, int* __restrict__ hist_nt,
                       u16* __restrict__ srank)
{
  int bid = blockIdx.x;
  if (bid >= PRECONV_NBLK) {
    int t = (bid - PRECONV_NBLK) * 256 + threadIdx.x;
    int lane = threadIdx.x & 63;
    if (t < N_EDGES) {
      int r = ei[t], c = ei[N_EDGES + t];
      int tr = ntp[r], tc = ntp[c];
      int key = (tr * 2 + tc) * N_NODES + r;
      int rk = atomicAdd(&hist[key], 1);
      srank[t] = (u16)rk;
    }
    bool valid = t < N_NODES;
    int ty = valid ? ntp[t] : -1;
    unsigned long long m0 = __ballot(ty == 0);
    unsigned long long m1 = __ballot(ty == 1);
    if (lane == 0) {
      int c0 = __popcll(m0), c1 = __popcll(m1);
      if (c0) atomicAdd(&hist_nt[0], c0);
      if (c1) atomicAdd(&hist_nt[1], c1);
    }
    return;
  }
  int t = bid * 256 + threadIdx.x;
  if (t < NX) { x0b[t] = f2b(x[t]); return; }
  t -= NX;
  if (t < NW1T) {
    int p = t / 36864, r = t % 36864; int k = r >> 7, n = r & 127;
    float v = (k < 272) ? ew1[(p * 272 + k) * 128 + n] : 0.f;
    wt1t[(p * 128 + n) * 288 + k] = f2b(v);
    return;
  }
  t -= NW1T;
  if (t < NW2T) {
    int p = t >> 14, r = t & 16383; int k = r >> 7, n = r & 127;
    wt2t[(p * 128 + n) * 128 + k] = f2b(ew2[(p * 128 + k) * 128 + n]);
    return;
  }
  t -= NW2T;
  if (t < NN1) {
    int ty = t >> 15, r = t & 32767; int k = r >> 7, n = r & 127;
    nw1t[(ty * 128 + n) * 256 + k] = f2b(nw1[(ty * 256 + k) * 128 + n]);
    return;
  }
  t -= NN1;
  if (t < NN2) {
    int ty = t >> 14, r = t & 16383; int k = r >> 7, n = r & 127;
    nw2t[(ty * 128 + n) * 128 + k] = f2b(nw2[(ty * 128 + k) * 128 + n]);
  }
}

__global__ void k_scan1(const int* __restrict__ hist, int* __restrict__ parts)
{
  __shared__ int s[256];
  int i = blockIdx.x * 256 + threadIdx.x;
  s[threadIdx.x] = (i < NBINS) ? hist[i] : 0;
  __syncthreads();
  for (int off = 128; off > 0; off >>= 1) {
    if (threadIdx.x < off) s[threadIdx.x] += s[threadIdx.x + off];
    __syncthreads();
  }
  if (threadIdx.x == 0) parts[blockIdx.x] = s[0];
}

__global__ void k_scan2(int* __restrict__ parts)
{
  __shared__ int s[512];
  int t = threadIdx.x;
  int v = (t < SCAN_NBLK) ? parts[t] : 0;
  s[t] = v; __syncthreads();
  for (int off = 1; off < 512; off <<= 1) {
    int xv = (t >= off) ? s[t - off] : 0;
    __syncthreads();
    s[t] += xv;
    __syncthreads();
  }
  if (t < SCAN_NBLK) parts[t] = s[t] - v;
}

__global__ void k_scan3(const int* __restrict__ hist, const int* __restrict__ parts,
                        int* __restrict__ bstart)
{
  __shared__ int s[256];
  int i = blockIdx.x * 256 + threadIdx.x;
  int v = (i < NBINS) ? hist[i] : 0;
  s[threadIdx.x] = v; __syncthreads();
  for (int off = 1; off < 256; off <<= 1) {
    int xv = (threadIdx.x >= off) ? s[threadIdx.x - off] : 0;
    __syncthreads();
    s[threadIdx.x] += xv;
    __syncthreads();
  }
  int excl = s[threadIdx.x] - v + parts[blockIdx.x];
  if (i < NBINS) bstart[i] = excl;
  if (i == 0) bstart[NBINS] = N_EDGES;
}

// ---------------- pass B: placement ----------------
__global__ void k_place(const int* __restrict__ ei, const int* __restrict__ ntp,
                        const u16* __restrict__ srank, const int* __restrict__ bstart,
                        int2* __restrict__ sedge,
                        int* __restrict__ cur_nt, const int* __restrict__ hist_nt,
                        int* __restrict__ nidx)
{
  int t = blockIdx.x * 256 + threadIdx.x;
  int lane = threadIdx.x & 63;
  if (t < N_EDGES) {
    int r = ei[t], c = ei[N_EDGES + t];
    int tr = ntp[r], tc = ntp[c];
    int key = (tr * 2 + tc) * N_NODES + r;
    int pos = bstart[key] + (int)srank[t];
    int2 v; v.x = r | (c << 15); v.y = t;
    sedge[pos] = v;
  }
  bool valid = t < N_NODES;
  int ty = valid ? ntp[t] : -1;
  unsigned long long m0 = __ballot(ty == 0);
  unsigned long long m1 = __ballot(ty == 1);
  int b0 = 0, b1 = 0;
  if (lane == 0) {
    int c0 = __popcll(m0), c1 = __popcll(m1);
    if (c0) b0 = atomicAdd(&cur_nt[0], c0);
    if (c1) b1 = atomicAdd(&cur_nt[1], c1);
  }
  b0 = __shfl(b0, 0); b1 = __shfl(b1, 0);
  if (valid) {
    unsigned long long lt = (1ull << lane) - 1ull;
    int pos = (ty == 0) ? (b0 + __popcll(m0 & lt))
                        : (hist_nt[0] + b1 + __popcll(m1 & lt));
    nidx[pos] = t;
  }
}

// ---------------- edge MLP (round-14 best): chunk-major LDS, meta prefetch, span mapping ----------------
__launch_bounds__(512, 2)
__global__ void k_edge(const u16* __restrict__ x0b, const float* __restrict__ ea,
                       const u16* __restrict__ wt1t, const u16* __restrict__ wt2t,
                       const float* __restrict__ eb1, const float* __restrict__ eb2,
                       const int* __restrict__ bstart, const int2* __restrict__ sedge,
                       u16* __restrict__ h2s)
{
  __shared__ u16 sW1[36 * 1024];      // [chunk][n 128][8]
  __shared__ u16 sW2[16 * 1024];      // [chunk][n 128][8]
  __shared__ u16 slab[8][16 * 128];   // per-wave [chunk 16][llo 16][8]
  __shared__ float sEb1[128];
  __shared__ float sEb2[128];

  const int p    = blockIdx.y;
  const int tid  = threadIdx.x;
  const int lane = tid & 63;
  const int wv   = tid >> 6;
  const int llo  = lane & 15;
  const int lhi  = lane >> 4;

  const int base_p = bstart[p * N_NODES];
  const int end_p  = bstart[(p + 1) * N_NODES];

  // stage weights once per block (chunk-major)
  for (int i = tid; i < 128 * 36; i += 512) {
    int n = i / 36, c = i % 36;
    *(u32x4*)&sW1[(c * 128 + n) * 8] = *(const u32x4*)&wt1t[(p * 128 + n) * 288 + c * 8];
  }
  for (int i = tid; i < 128 * 16; i += 512) {
    int n = i >> 4, c = i & 15;
    *(u32x4*)&sW2[(c * 128 + n) * 8] = *(const u32x4*)&wt2t[(p * 128 + n) * 128 + c * 8];
  }
  if (tid < 128) sEb1[tid] = eb1[p * 128 + tid];
  else if (tid < 256) sEb2[tid - 128] = eb2[p * 128 + tid - 128];
  __syncthreads();   // only block-wide barrier

  u16* myslab = &slab[wv][0];
  const int np = end_p - base_p;
  if (np <= 0) return;
  const int ngrp = (np + 31) >> 5;

  // contiguous span of 32-edge groups for this block (row-sorted -> L2 locality)
  const int g0 = (int)(((long long)blockIdx.x * ngrp) / 64);
  const int g1 = (int)(((long long)(blockIdx.x + 1) * ngrp) / 64);

  int g = g0 + wv;
  if (g >= g1) return;

  // prologue: prefetch first tile's metadata
  int2 mN0 = {0, 0}, mN1 = {0, 0};
  {
    const int es = base_p + g * 32;
    int q0 = es + llo;      q0 = q0 < end_p ? q0 : end_p - 1;
    int q1 = es + 16 + llo; q1 = q1 < end_p ? q1 : end_p - 1;
    mN0 = sedge[q0];
    mN1 = sedge[q1];
  }

  for (; g < g1; g += 8) {
    const int es   = base_p + g * 32;
    const int pos0 = es + llo;
    const int pos1 = pos0 + 16;
    const int row0 = mN0.x & 32767, col0 = mN0.x >> 15, eid0 = mN0.y;
    const int row1 = mN1.x & 32767, col1 = mN1.x >> 15, eid1 = mN1.y;

    // issue gathers for CURRENT tile immediately (critical path)
    bf16x8 xr[2][4], xc[2][4], eaf[2];
    #pragma unroll
    for (int ck = 0; ck < 4; ++ck) {
      xr[0][ck] = *(const bf16x8*)&x0b[row0 * 128 + ck * 32 + lhi * 8];
      xc[0][ck] = *(const bf16x8*)&x0b[col0 * 128 + ck * 32 + lhi * 8];
      xr[1][ck] = *(const bf16x8*)&x0b[row1 * 128 + ck * 32 + lhi * 8];
      xc[1][ck] = *(const bf16x8*)&x0b[col1 * 128 + ck * 32 + lhi * 8];
    }
    {
      u32x4 pk0 = (u32x4){0u, 0u, 0u, 0u};
      u32x4 pk1 = (u32x4){0u, 0u, 0u, 0u};
      if (lhi < 2) {
        f32x4 f0 = *(const f32x4*)&ea[eid0 * 16 + lhi * 8];
        f32x4 f1 = *(const f32x4*)&ea[eid0 * 16 + lhi * 8 + 4];
        pk0[0] = cvtpk(f0[0], f0[1]); pk0[1] = cvtpk(f0[2], f0[3]);
        pk0[2] = cvtpk(f1[0], f1[1]); pk0[3] = cvtpk(f1[2], f1[3]);
        f32x4 g0v = *(const f32x4*)&ea[eid1 * 16 + lhi * 8];
        f32x4 g1v = *(const f32x4*)&ea[eid1 * 16 + lhi * 8 + 4];
        pk1[0] = cvtpk(g0v[0], g0v[1]); pk1[1] = cvtpk(g0v[2], g0v[3]);
        pk1[2] = cvtpk(g1v[0], g1v[1]); pk1[3] = cvtpk(g1v[2], g1v[3]);
      }
      __builtin_memcpy(&eaf[0], &pk0, 16);
      __builtin_memcpy(&eaf[1], &pk1, 16);
    }

    // prefetch NEXT tile's metadata (independent; completes under compute)
    {
      const int gnext = g + 8;
      if (gnext < g1) {
        const int esn = base_p + gnext * 32;
        int q0 = esn + llo;      q0 = q0 < end_p ? q0 : end_p - 1;
        int q1 = esn + 16 + llo; q1 = q1 < end_p ? q1 : end_p - 1;
        mN0 = sedge[q0];
        mN1 = sedge[q1];
      }
    }

    // ---- layer 1: K = 256 (row|col) + 32 (ea) ----
    f32x4 acc[8][2];
    #pragma unroll
    for (int i = 0; i < 8; ++i) {
      acc[i][0] = (f32x4){0.f, 0.f, 0.f, 0.f};
      acc[i][1] = (f32x4){0.f, 0.f, 0.f, 0.f};
    }

    #pragma unroll
    for (int ck = 0; ck < 4; ++ck) {
      #pragma unroll
      for (int i = 0; i < 8; ++i) {
        bf16x8 wa = *(const bf16x8*)&sW1[((ck * 4 + lhi) * 128 + i * 16 + llo) * 8];
        acc[i][0] = __builtin_amdgcn_mfma_f32_16x16x32_bf16(wa, xr[0][ck], acc[i][0], 0, 0, 0);
        acc[i][1] = __builtin_amdgcn_mfma_f32_16x16x32_bf16(wa, xr[1][ck], acc[i][1], 0, 0, 0);
      }
    }
    #pragma unroll
    for (int ck = 0; ck < 4; ++ck) {
      #pragma unroll
      for (int i = 0; i < 8; ++i) {
        bf16x8 wb = *(const bf16x8*)&sW1[((16 + ck * 4 + lhi) * 128 + i * 16 + llo) * 8];
        acc[i][0] = __builtin_amdgcn_mfma_f32_16x16x32_bf16(wb, xc[0][ck], acc[i][0], 0, 0, 0);
        acc[i][1] = __builtin_amdgcn_mfma_f32_16x16x32_bf16(wb, xc[1][ck], acc[i][1], 0, 0, 0);
      }
    }
    #pragma unroll
    for (int i = 0; i < 8; ++i) {
      bf16x8 wce = *(const bf16x8*)&sW1[((32 + lhi) * 128 + i * 16 + llo) * 8];
      acc[i][0] = __builtin_amdgcn_mfma_f32_16x16x32_bf16(wce, eaf[0], acc[i][0], 0, 0, 0);
      acc[i][1] = __builtin_amdgcn_mfma_f32_16x16x32_bf16(wce, eaf[1], acc[i][1], 0, 0, 0);
    }

    // h1 = relu(acc+eb1): transpose via per-wave slab (chunk-major), collect B-frags
    bf16x8 h1f[2][4];
    #pragma unroll
    for (int j = 0; j < 2; ++j) {
      #pragma unroll
      for (int i = 0; i < 8; ++i) {
        const f32x4 bb = *(const f32x4*)&sEb1[i * 16 + lhi * 4];
        float v0 = acc[i][j][0] + bb[0]; v0 = v0 > 0.f ? v0 : 0.f;
        float v1 = acc[i][j][1] + bb[1]; v1 = v1 > 0.f ? v1 : 0.f;
        float v2 = acc[i][j][2] + bb[2]; v2 = v2 > 0.f ? v2 : 0.f;
        float v3 = acc[i][j][3] + bb[3]; v3 = v3 > 0.f ? v3 : 0.f;
        u32x2 pk; pk[0] = cvtpk(v0, v1); pk[1] = cvtpk(v2, v3);
        *(u32x2*)&myslab[((2 * i + (lhi >> 1)) * 16 + llo) * 8 + (lhi & 1) * 4] = pk;
      }
      #pragma unroll
      for (int ck = 0; ck < 4; ++ck)
        h1f[j][ck] = *(const bf16x8*)&myslab[((ck * 4 + lhi) * 16 + llo) * 8];
    }

    // ---- layer 2: K = 128, W2 from LDS (chunk-major) ----
    f32x4 o[8][2];
    #pragma unroll
    for (int i = 0; i < 8; ++i) {
      o[i][0] = (f32x4){0.f, 0.f, 0.f, 0.f};
      o[i][1] = (f32x4){0.f, 0.f, 0.f, 0.f};
    }
    #pragma unroll
    for (int ck = 0; ck < 4; ++ck) {
      #pragma unroll
      for (int i = 0; i < 8; ++i) {
        bf16x8 w2f = *(const bf16x8*)&sW2[((ck * 4 + lhi) * 128 + i * 16 + llo) * 8];
        o[i][0] = __builtin_amdgcn_mfma_f32_16x16x32_bf16(w2f, h1f[0][ck], o[i][0], 0, 0, 0);
        o[i][1] = __builtin_amdgcn_mfma_f32_16x16x32_bf16(w2f, h1f[1][ck], o[i][1], 0, 0, 0);
      }
    }

    // h2 = relu(o + eb2) -> packed 8B stores at sorted positions
    #pragma unroll
    for (int i = 0; i < 8; ++i) {
      const f32x4 bb = *(const f32x4*)&sEb2[i * 16 + lhi * 4];
      {
        float v0 = o[i][0][0] + bb[0]; v0 = v0 > 0.f ? v0 : 0.f;
        float v1 = o[i][0][1] + bb[1]; v1 = v1 > 0.f ? v1 : 0.f;
        float v2 = o[i][0][2] + bb[2]; v2 = v2 > 0.f ? v2 : 0.f;
        float v3 = o[i][0][3] + bb[3]; v3 = v3 > 0.f ? v3 : 0.f;
        u32x2 pk; pk[0] = cvtpk(v0, v1); pk[1] = cvtpk(v2, v3);
        if (pos0 < end_p) *(u32x2*)&h2s[pos0 * 128 + i * 16 + lhi * 4] = pk;
      }
      {
        float v0 = o[i][1][0] + bb[0]; v0 = v0 > 0.f ? v0 : 0.f;
        float v1 = o[i][1][1] + bb[1]; v1 = v1 > 0.f ? v1 : 0.f;
        float v2 = o[i][1][2] + bb[2]; v2 = v2 > 0.f ? v2 : 0.f;
        float v3 = o[i][1][3] + bb[3]; v3 = v3 > 0.f ? v3 : 0.f;
        u32x2 pk; pk[0] = cvtpk(v0, v1); pk[1] = cvtpk(v2, v3);
        if (pos1 < end_p) *(u32x2*)&h2s[pos1 * 128 + i * 16 + lhi * 4] = pk;
      }
    }
  }
}

// ---------------- node MLP: persistent blocks + 2-wide unrolled run-sum (MLP doubled) ----------------
__launch_bounds__(512, 1)
__global__ void k_node(const u16* __restrict__ x0b, const float* __restrict__ xf,
                       const u16* __restrict__ h2s,
                       const u16* __restrict__ nw1t, const u16* __restrict__ nw2t,
                       const float* __restrict__ nb1, const float* __restrict__ nb2,
                       const int* __restrict__ bstart,
                       const int* __restrict__ nidx, const int* __restrict__ hist_nt,
                       float* __restrict__ out)
{
  const int ty    = blockIdx.y;
  const int cnt0  = hist_nt[0];
  const int cnt_t = ty ? (N_NODES - cnt0) : cnt0;
  const int base_t = ty ? cnt0 : 0;

  __shared__ u16 sNIN[64 * 264];
  __shared__ u16 sNW1[128 * 264];
  __shared__ u16 sNW2[128 * 136];
  __shared__ float sNb1[128];
  __shared__ float sNb2[128];
  __shared__ int sNid[64];

  const int tid  = threadIdx.x;
  const int lane = tid & 63;
  const int wid  = tid >> 6;
  const int llo  = lane & 15;
  const int lhi  = lane >> 4;

  for (int i = tid; i < 128 * 256; i += 512) {
    int n = i >> 8, k = i & 255;
    sNW1[n * 264 + k] = nw1t[(ty * 128 + n) * 256 + k];
  }
  for (int i = tid; i < 128 * 128; i += 512) {
    int n = i >> 7, k = i & 127;
    sNW2[n * 136 + k] = nw2t[(ty * 128 + n) * 128 + k];
  }
  if (tid < 128) { sNb1[tid] = nb1[ty * 128 + tid]; sNb2[tid] = nb2[ty * 128 + tid]; }
  __syncthreads();

  for (int t0 = blockIdx.x * 64; t0 < cnt_t; t0 += gridDim.x * 64) {
    const int cnt = min(64, cnt_t - t0);
    if (tid < 64) {
      int nid = 0;
      if (tid < cnt) nid = nidx[base_t + t0 + tid];
      sNid[tid] = nid;
    }
    __syncthreads();

    // stage node_in = [x0 | agg]; agg = 2-wide unrolled sum over contiguous h2 runs
    {
      const int m = tid >> 3, qq = tid & 7;
      const int nid = sNid[m];
      const u16* xs = &x0b[nid * 128 + qq * 16];
      u16* dst = &sNIN[m * 264 + qq * 16];
      #pragma unroll
      for (int j = 0; j < 2; ++j) *(u32x4*)(dst + j * 8) = *(const u32x4*)(xs + j * 8);

      float a[16];
      #pragma unroll
      for (int j = 0; j < 16; ++j) a[j] = 0.f;
      #pragma unroll
      for (int pr = 0; pr < 2; ++pr) {
        const int key = (ty * 2 + pr) * N_NODES + nid;
        const int s = bstart[key], e = bstart[key + 1];
        int pos = s;
        // 2-wide: two independent 32B load pairs in flight per step
        for (; pos + 2 <= e; pos += 2) {
          const u16* hp0 = &h2s[pos * 128 + qq * 16];
          const u16* hp1 = &h2s[(pos + 1) * 128 + qq * 16];
          u32x4 va0 = *(const u32x4*)(hp0);
          u32x4 vb0 = *(const u32x4*)(hp0 + 8);
          u32x4 va1 = *(const u32x4*)(hp1);
          u32x4 vb1 = *(const u32x4*)(hp1 + 8);
          #pragma unroll
          for (int w = 0; w < 4; ++w) {
            unsigned u0 = va0[w], u1 = va1[w];
            a[w * 2 + 0] += b2f((u16)(u0 & 0xFFFFu)) + b2f((u16)(u1 & 0xFFFFu));
            a[w * 2 + 1] += b2f((u16)(u0 >> 16))     + b2f((u16)(u1 >> 16));
            unsigned v0 = vb0[w], v1 = vb1[w];
            a[8 + w * 2 + 0] += b2f((u16)(v0 & 0xFFFFu)) + b2f((u16)(v1 & 0xFFFFu));
            a[8 + w * 2 + 1] += b2f((u16)(v0 >> 16))     + b2f((u16)(v1 >> 16));
          }
        }
        if (pos < e) {
          const u16* hp = &h2s[pos * 128 + qq * 16];
          u32x4 va = *(const u32x4*)(hp);
          u32x4 vb = *(const u32x4*)(hp + 8);
          #pragma unroll
          for (int w = 0; w < 4; ++w) {
            unsigned u0 = va[w];
            a[w * 2 + 0] += b2f((u16)(u0 & 0xFFFFu));
            a[w * 2 + 1] += b2f((u16)(u0 >> 16));
            unsigned v0 = vb[w];
            a[8 + w * 2 + 0] += b2f((u16)(v0 & 0xFFFFu));
            a[8 + w * 2 + 1] += b2f((u16)(v0 >> 16));
          }
        }
      }
      u16* ad = &sNIN[m * 264 + 128 + qq * 16];
      #pragma unroll
      for (int j = 0; j < 8; ++j) {
        unsigned pk = cvtpk(a[2 * j], a[2 * j + 1]);
        *(unsigned*)(ad + 2 * j) = pk;
      }
    }
    __syncthreads();

    f32x4 acc[4];
    #pragma unroll
    for (int i = 0; i < 4; ++i) acc[i] = (f32x4){0.f, 0.f, 0.f, 0.f};

    #pragma unroll
    for (int ck = 0; ck < 8; ++ck) {
      const int kk = ck * 32 + lhi * 8;
      bf16x8 a[4], b;
      #pragma unroll
      for (int i = 0; i < 4; ++i)
        a[i] = *(const bf16x8*)&sNIN[(i * 16 + llo) * 264 + kk];
      b = *(const bf16x8*)&sNW1[(wid * 16 + llo) * 264 + kk];
      #pragma unroll
      for (int i = 0; i < 4; ++i)
        acc[i] = __builtin_amdgcn_mfma_f32_16x16x32_bf16(a[i], b, acc[i], 0, 0, 0);
    }
    __syncthreads();

    u16* sH1 = sNIN;
    #pragma unroll
    for (int i = 0; i < 4; ++i) {
      const int c = wid * 16 + llo;
      const float bias = sNb1[c];
      #pragma unroll
      for (int r = 0; r < 4; ++r) {
        const int m = i * 16 + lhi * 4 + r;
        float v = acc[i][r] + bias;
        v = v > 0.f ? v : 0.f;
        sH1[m * 136 + c] = f2b(v);
      }
    }
    __syncthreads();

    #pragma unroll
    for (int i = 0; i < 4; ++i) acc[i] = (f32x4){0.f, 0.f, 0.f, 0.f};

    #pragma unroll
    for (int ck = 0; ck < 4; ++ck) {
      const int kk = ck * 32 + lhi * 8;
      bf16x8 a[4], b;
      #pragma unroll
      for (int i = 0; i < 4; ++i)
        a[i] = *(const bf16x8*)&sH1[(i * 16 + llo) * 136 + kk];
      b = *(const bf16x8*)&sNW2[(wid * 16 + llo) * 136 + kk];
      #pragma unroll
      for (int i = 0; i < 4; ++i)
        acc[i] = __builtin_amdgcn_mfma_f32_16x16x32_bf16(a[i], b, acc[i], 0, 0, 0);
    }

    #pragma unroll
    for (int i = 0; i < 4; ++i) {
      const int c = wid * 16 + llo;
      const float bias = sNb2[c];
      #pragma unroll
      for (int r = 0; r < 4; ++r) {
        const int m = i * 16 + lhi * 4 + r;
        if (m < cnt) {
          const int nid = sNid[m];
          out[nid * 128 + c] = acc[i][r] + bias + xf[nid * 128 + c];
        }
      }
    }
    __syncthreads();
  }
}

// ---------------- launch ----------------
extern "C" void kernel_launch(void* const* d_in, const int* in_sizes, int n_in,
                              void* d_out, int out_size, void* d_ws, size_t ws_size,
                              hipStream_t stream)
{
  const float* x   = (const float*)d_in[0];
  const int*   ei  = (const int*)d_in[1];
  const float* ea  = (const float*)d_in[2];
  const int*   ntp = (const int*)d_in[3];
  const float* ew1 = (const float*)d_in[4];
  const float* eb1 = (const float*)d_in[5];
  const float* ew2 = (const float*)d_in[6];
  const float* eb2 = (const float*)d_in[7];
  const float* nw1 = (const float*)d_in[8];
  const float* nb1 = (const float*)d_in[9];
  const float* nw2 = (const float*)d_in[10];
  const float* nb2 = (const float*)d_in[11];

  char* ws = (char*)d_ws;
  int*  hist    = (int*)(ws + 0);          // 320000
  int*  hist_nt = (int*)(ws + 320000);     // 8
  int*  cur_nt  = (int*)(ws + 320008);     // 8
  int*  parts   = (int*)(ws + 320256);     // 1252
  int*  bstart  = (int*)(ws + 321792);     // 320004
  u16*  srank   = (u16*)(ws + 641824);     // 640000
  int2* sedge   = (int2*)(ws + 1281824);   // 2560000
  int*  nidx    = (int*)(ws + 3841824);    // 80000
  u16*  x0b     = (u16*)(ws + 3921824);    // 5120000
  u16*  wt1t    = (u16*)(ws + 9041824);    // 294912
  u16*  wt2t    = (u16*)(ws + 9336736);    // 131072
  u16*  nw1t    = (u16*)(ws + 9467808);    // 131072
  u16*  nw2t    = (u16*)(ws + 9598880);    // 65536
  u16*  h2s     = (u16*)(ws + 9664416);    // 81920000 -> total ~91.6 MB (known-good)

  hipMemsetAsync(ws, 0, 320016, stream);
  k_prep<<<PRECONV_NBLK + HIST_NBLK, 256, 0, stream>>>(
      x, ew1, ew2, nw1, nw2, x0b, wt1t, wt2t, nw1t, nw2t,
      ei, ntp, hist, hist_nt, srank);
  k_scan1<<<SCAN_NBLK, 256, 0, stream>>>(hist, parts);
  k_scan2<<<1, 512, 0, stream>>>(parts);
  k_scan3<<<SCAN_NBLK, 256, 0, stream>>>(hist, parts, bstart);
  k_place<<<1250, 256, 0, stream>>>(ei, ntp, srank, bstart, sedge, cur_nt, hist_nt, nidx);
  k_edge<<<dim3(64, 4), 512, 0, stream>>>(x0b, ea, wt1t, wt2t, eb1, eb2, bstart, sedge, h2s);
  k_node<<<dim3(160, 2), 512, 0, stream>>>(x0b, x, h2s, nw1t, nw2t, nb1, nb2, bstart, nidx, hist_nt, (float*)d_out);
}